// Round 3
// baseline (140.853 us; speedup 1.0000x reference)
//
#include <hip/hip_runtime.h>

typedef unsigned short u16;
typedef unsigned int u32;
typedef __bf16 bfx8 __attribute__((ext_vector_type(8)));
typedef float f32x4 __attribute__((ext_vector_type(4)));

#define HIDDEN 1024
#define HEADS 16
#define HDIM 64
#define SEQ 2048
#define LOG2E 1.44269504f

__device__ __forceinline__ u16 f2bf(float f) {
  u32 u = __builtin_bit_cast(u32, f);
  u += 0x7fffu + ((u >> 16) & 1u);
  return (u16)(u >> 16);
}
__device__ __forceinline__ float bf2f(u16 v) {
  u32 u = ((u32)v) << 16;
  return __builtin_bit_cast(float, u);
}

#define GLOAD_LDS16(g, l)                                                       \
  __builtin_amdgcn_global_load_lds(                                             \
      (const __attribute__((address_space(1))) void*)(g),                       \
      (__attribute__((address_space(3))) void*)(l), 16, 0, 0)

#define MFMA16(a, b, c) __builtin_amdgcn_mfma_f32_16x16x32_bf16(a, b, c, 0, 0, 0)
#define SBAR() __builtin_amdgcn_s_barrier()
#define SCHEDB() __builtin_amdgcn_sched_barrier(0)
#define LGKM0()                                            \
  {                                                        \
    asm volatile("s_waitcnt lgkmcnt(0)" ::: "memory");     \
    SCHEDB();                                              \
  }
#define VMCNT(n) asm volatile("s_waitcnt vmcnt(" #n ")" ::: "memory")

// ---------------- cast hidden fp32 -> bf16 ----------------
__global__ __launch_bounds__(256) void cast_bf16_kernel(
    const float* __restrict__ src, u16* __restrict__ dst, int n4) {
  int idx = blockIdx.x * blockDim.x + threadIdx.x;
  int stride = gridDim.x * blockDim.x;
  for (int i = idx; i < n4; i += stride) {
    float4 v = ((const float4*)src)[i];
    ushort4 o;
    o.x = f2bf(v.x); o.y = f2bf(v.y); o.z = f2bf(v.z); o.w = f2bf(v.w);
    ((ushort4*)dst)[i] = o;
  }
}

// ------------- transpose-cast 4 weights W[k][n] fp32 -> Wt[n][k] bf16 -------------
__global__ __launch_bounds__(256) void transpose_cast4_kernel(
    const float* __restrict__ W0, const float* __restrict__ W1,
    const float* __restrict__ W2, const float* __restrict__ W3,
    u16* __restrict__ dstbase) {
  __shared__ u16 tile[64][65];
  const float* W = blockIdx.z == 0 ? W0 : blockIdx.z == 1 ? W1
                  : blockIdx.z == 2 ? W2 : W3;
  u16* Wt = dstbase + (size_t)blockIdx.z * HIDDEN * HIDDEN;
  const int kt = blockIdx.y * 64, nt = blockIdx.x * 64;
  const int t = threadIdx.x;
#pragma unroll
  for (int it = 0; it < 16; ++it) {
    int kl = it * 4 + (t >> 6), nl = t & 63;
    tile[kl][nl] = f2bf(W[(size_t)(kt + kl) * HIDDEN + nt + nl]);
  }
  __syncthreads();
#pragma unroll
  for (int it = 0; it < 16; ++it) {
    int nl = it * 4 + (t >> 6), kl = t & 63;
    Wt[(size_t)(nt + nl) * HIDDEN + kt + kl] = tile[kl][nl];
  }
}

// =================================================================
// 256x256x64 8-phase bf16 GEMM (T3+T4+T5), QKV epilogue.
// LDS halves stored [256 rows][32 k-cols] (64B rows) -> ds_read_b128
// A/B-fragment reads are conflict-free by construction (16 rows x 4
// slots tile all 32 banks exactly).
// =================================================================
#define ASOFF(buf, ks) ((buf)*16384 + (ks)*8192)
#define BSOFF(buf, ks) (32768 + (buf)*16384 + (ks)*8192)

// stage one 16KB half-tile: 8 waves x 2 chunks x 1KB. gbase in u16 elements,
// global row stride 1024 u16. LDS dest linear (wave-uniform base + lane*16B).
#define STG(gbase, ldsoff)                                                     \
  {                                                                            \
    const u16* _g = (gbase);                                                   \
    u16* _l = lds + (ldsoff);                                                  \
    GLOAD_LDS16(_g + (size_t)((wave * 2 + 0) * 16 + (lane >> 2)) * 1024 +      \
                    (lane & 3) * 8,                                            \
                _l + (wave * 2 + 0) * 512);                                    \
    GLOAD_LDS16(_g + (size_t)((wave * 2 + 1) * 16 + (lane >> 2)) * 1024 +      \
                    (lane & 3) * 8,                                            \
                _l + (wave * 2 + 1) * 512);                                    \
  }

#define LDA(buf, ks)                                                           \
  _Pragma("unroll") for (int _mf = 0; _mf < 8; ++_mf)                          \
      af[_mf] = *(const bfx8*)(lds + ASOFF(buf, ks) +                          \
                               (wmbase + _mf * 16 + li) * 32 + lg * 8);

#define LDB(buf, ks, nh)                                                       \
  bf0 = *(const bfx8*)(lds + BSOFF(buf, ks) +                                  \
                       (wnbase + (nh)*32 + li) * 32 + lg * 8);                 \
  bf1 = *(const bfx8*)(lds + BSOFF(buf, ks) +                                  \
                       (wnbase + (nh)*32 + 16 + li) * 32 + lg * 8);

#define QMFMA(nh)                                                              \
  __builtin_amdgcn_s_setprio(1);                                               \
  _Pragma("unroll") for (int _mf = 0; _mf < 8; ++_mf) {                        \
    acc[_mf][(nh)*2] = MFMA16(af[_mf], bf0, acc[_mf][(nh)*2]);                 \
    acc[_mf][(nh)*2 + 1] = MFMA16(af[_mf], bf1, acc[_mf][(nh)*2 + 1]);         \
  }                                                                            \
  __builtin_amdgcn_s_setprio(0);

// One K-tile = 4 phases. Staging stream (tile t): ph0: B-ks0(t+1),
// ph1: A-ks1(t+1), ph2: B-ks1(t+1), ph3: A-ks0(t+2). Counted waits:
// end-ph1 vmcnt(6|0), end-ph3 vmcnt(6|4|-).
#define TILE(c, ktv, S1, S2, W3)                                               \
  {                                                                            \
    /* phase 0: ks0 x N-half0 */                                               \
    LDA(c, 0); LDB(c, 0, 0);                                                   \
    if (S1) STG(Bg + (ktv) + 64, BSOFF(1 - (c), 0));                           \
    SBAR(); LGKM0(); QMFMA(0); SCHEDB(); SBAR();                               \
    /* phase 1: ks0 x N-half1 */                                               \
    LDB(c, 0, 1);                                                              \
    if (S1) STG(Ag + (ktv) + 96, ASOFF(1 - (c), 1));                           \
    SBAR(); LGKM0(); QMFMA(1); SCHEDB();                                       \
    if (S1) { VMCNT(6); } else { VMCNT(0); }                                   \
    SBAR();                                                                    \
    /* phase 2: ks1 x N-half0 */                                               \
    LDA(c, 1); LDB(c, 1, 0);                                                   \
    if (S1) STG(Bg + (ktv) + 96, BSOFF(1 - (c), 1));                           \
    SBAR(); LGKM0(); QMFMA(0); SCHEDB(); SBAR();                               \
    /* phase 3: ks1 x N-half1 */                                               \
    LDB(c, 1, 1);                                                              \
    if (S2) STG(Ag + (ktv) + 128, ASOFF(c, 0));                                \
    SBAR(); LGKM0(); QMFMA(1); SCHEDB();                                       \
    W3;                                                                        \
    SBAR();                                                                    \
  }

__global__ __launch_bounds__(512, 2) void gemm_qkv_256_kernel(
    const u16* __restrict__ A, const u16* __restrict__ Bt,
    const float* __restrict__ bq, const float* __restrict__ bk,
    const float* __restrict__ bv, u16* __restrict__ qo, u16* __restrict__ ko,
    u16* __restrict__ vto) {
  extern __shared__ u16 lds[];  // 128KB: A[2buf][2ks][256*32], B same
  const int tid = threadIdx.x;
  const int lane = tid & 63;
  const int wave = tid >> 6;   // 0..7
  const int wm = wave >> 2, wn = wave & 3;
  const int li = lane & 15, lg = lane >> 4;
  const int wmbase = wm * 128;
  const int wnbase = wn * 64;
  // 192 blocks = 8 XCDs x 24, bijective swizzle; bn fastest for A-panel reuse
  const int bid = blockIdx.x;
  const int wid = (bid & 7) * 24 + (bid >> 3);
  const int bm = wid / 12, bn = wid % 12;
  const int m0 = bm * 256, n0 = bn * 256;
  const u16* Ag = A + (size_t)m0 * 1024;
  const u16* Bg = Bt + (size_t)n0 * 1024;

  f32x4 acc[8][4];
  bfx8 af[8], bf0, bf1;
  const f32x4 zero = {0.f, 0.f, 0.f, 0.f};
#pragma unroll
  for (int mf = 0; mf < 8; ++mf)
#pragma unroll
    for (int nf = 0; nf < 4; ++nf) acc[mf][nf] = zero;

  // prologue: stream order A0(0) B0(0) A1(0) B1(0) A0(1); keep 6 in flight
  STG(Ag + 0, ASOFF(0, 0));
  STG(Bg + 0, BSOFF(0, 0));
  STG(Ag + 32, ASOFF(0, 1));
  STG(Bg + 32, BSOFF(0, 1));
  STG(Ag + 64, ASOFF(1, 0));
  VMCNT(6);
  SBAR();

  int kt = 0;
#pragma unroll 1
  for (int tt = 0; tt < 7; ++tt) {  // tiles 0..13
    TILE(0, kt, 1, 1, VMCNT(6));
    kt += 64;
    TILE(1, kt, 1, 1, VMCNT(6));
    kt += 64;
  }
  TILE(0, kt, 1, 0, VMCNT(4));  // tile 14: stages tile 15 halves only
  kt += 64;
  TILE(1, kt, 0, 0, {});        // tile 15: drain (vmcnt(0) at ph1)

  // epilogue: bias + q/k/v scatter (v transposed)
#pragma unroll
  for (int nf = 0; nf < 4; ++nf) {
    const int n = n0 + wnbase + nf * 16 + li;
    const int which = n >> 10;
    const int nn = n & 1023;
    const float bias = (which == 0 ? bq : which == 1 ? bk : bv)[nn];
    const int hh = nn >> 6, d = nn & 63;
#pragma unroll
    for (int mf = 0; mf < 8; ++mf) {
#pragma unroll
      for (int r = 0; r < 4; ++r) {
        const int m = m0 + wmbase + mf * 16 + lg * 4 + r;
        const int bb = m >> 11, s = m & (SEQ - 1);
        const int bh = bb * HEADS + hh;
        const u16 val = f2bf(acc[mf][nf][r] + bias);
        if (which == 0)      qo[((size_t)bh * SEQ + s) * HDIM + d] = val;
        else if (which == 1) ko[((size_t)bh * SEQ + s) * HDIM + d] = val;
        else                 vto[((size_t)bh * HDIM + d) * SEQ + s] = val;
      }
    }
  }
}

// ---------------- 128x128 m97 GEMM core (kept for the output projection) ----------------
__device__ __forceinline__ void gemm_core(const u16* __restrict__ A,
                                          const u16* __restrict__ Bt, int K,
                                          int m0, int n0, u16* As, u16* Bs,
                                          f32x4 acc[4][4]) {
  const int lane = threadIdx.x & 63;
  const int wave = threadIdx.x >> 6;
  const int wm = wave >> 1, wn = wave & 1;
  const int lrow = lane >> 2;
  const int lcol = (lane & 3) * 8;
  const f32x4 zero = {0.f, 0.f, 0.f, 0.f};
#pragma unroll
  for (int i = 0; i < 4; ++i)
#pragma unroll
    for (int j = 0; j < 4; ++j) acc[i][j] = zero;

  for (int kt = 0; kt < K; kt += 32) {
    __syncthreads();
#pragma unroll
    for (int c2 = 0; c2 < 2; ++c2) {
      const int c = wave * 2 + c2;
      const int r = c * 16 + lrow;
      GLOAD_LDS16(A + (size_t)(m0 + r) * K + kt + lcol, As + c * 512);
      GLOAD_LDS16(Bt + (size_t)(n0 + r) * K + kt + lcol, Bs + c * 512);
    }
    __syncthreads();
    bfx8 af[4], bf[4];
#pragma unroll
    for (int f = 0; f < 4; ++f) {
      af[f] = *(const bfx8*)(As + (wm * 64 + f * 16 + (lane & 15)) * 32 + (lane >> 4) * 8);
      bf[f] = *(const bfx8*)(Bs + (wn * 64 + f * 16 + (lane & 15)) * 32 + (lane >> 4) * 8);
    }
#pragma unroll
    for (int fm = 0; fm < 4; ++fm)
#pragma unroll
      for (int fn = 0; fn < 4; ++fn)
        acc[fm][fn] = MFMA16(af[fm], bf[fn], acc[fm][fn]);
  }
}

// ---------------- output projection ----------------
__global__ __launch_bounds__(256) void gemm_out_kernel(
    const u16* __restrict__ A, const u16* __restrict__ Bt,
    const float* __restrict__ bo, float* __restrict__ out) {
  __shared__ alignas(16) u16 As[128 * 32];
  __shared__ alignas(16) u16 Bs[128 * 32];
  f32x4 acc[4][4];
  const int m0 = blockIdx.y * 128, n0 = blockIdx.x * 128;
  gemm_core(A, Bt, HIDDEN, m0, n0, As, Bs, acc);
  const int lane = threadIdx.x & 63;
  const int wave = threadIdx.x >> 6;
  const int wm = wave >> 1, wn = wave & 1;
#pragma unroll
  for (int fm = 0; fm < 4; ++fm)
#pragma unroll
    for (int fn = 0; fn < 4; ++fn) {
      const int n = n0 + wn * 64 + fn * 16 + (lane & 15);
      const float bias = bo[n];
#pragma unroll
      for (int r = 0; r < 4; ++r) {
        const int m = m0 + wm * 64 + fm * 16 + (lane >> 4) * 4 + r;
        out[(size_t)m * HIDDEN + n] = acc[fm][fn][r] + bias;
      }
    }
}

// ---------------- sliding-window + global-token attention (v2) ----------------
#define ATTN_STEP(KFC, KFN, PAR)                                                 \
  {                                                                             \
    const int j0 = wlo + (c << 5);                                              \
    int sidx = j0 + lg * 8;                                                     \
    if (sidx > SEQ - 8) sidx = SEQ - 8;                                         \
    const bfx8 vf0 = *(const bfx8*)(vb + (size_t)(li) * SEQ + sidx);            \
    const bfx8 vf1 = *(const bfx8*)(vb + (size_t)(16 + li) * SEQ + sidx);       \
    const bfx8 vf2 = *(const bfx8*)(vb + (size_t)(32 + li) * SEQ + sidx);       \
    const bfx8 vf3 = *(const bfx8*)(vb + (size_t)(48 + li) * SEQ + sidx);       \
    if (c + 1 < nc) {                                                           \
      const int j1 = j0 + 32;                                                   \
      int ja = j1 + li;      if (ja > SEQ - 1) ja = SEQ - 1;                    \
      int jb = j1 + 16 + li; if (jb > SEQ - 1) jb = SEQ - 1;                    \
      KFN[0] = *(const bfx8*)(kb + (size_t)ja * HDIM + lg * 8);                 \
      KFN[1] = *(const bfx8*)(kb + (size_t)ja * HDIM + 32 + lg * 8);            \
      KFN[2] = *(const bfx8*)(kb + (size_t)jb * HDIM + lg * 8);                 \
      KFN[3] = *(const bfx8*)(kb + (size_t)jb * HDIM + 32 + lg * 8);            \
    }                                                                           \
    f32x4 s0 = zero, s1 = zero;                                                 \
    s0 = MFMA16(qa[0], KFC[0], s0);                                             \
    s0 = MFMA16(qa[1], KFC[1], s0);                                             \
    s1 = MFMA16(qa[0], KFC[2], s1);                                             \
    s1 = MFMA16(qa[1], KFC[3], s1);                                             \
    const bool interior = (j0 >= i0 + 15 - half) && (j0 + 31 <= i0 + half) &&   \
                          (j0 + 31 <= SEQ - 1);                                 \
    if (interior) {                                                             \
      _Pragma("unroll") for (int r = 0; r < 4; ++r) {                           \
        const float p0 = exp2f(s0[r] * SCL);                                    \
        const float p1 = exp2f(s1[r] * SCL);                                    \
        lr[r] += p0 + p1;                                                       \
        P[PAR][lg * 4 + r][li] = f2bf(p0);                                      \
        P[PAR][lg * 4 + r][16 + li] = f2bf(p1);                                 \
      }                                                                         \
    } else {                                                                    \
      _Pragma("unroll") for (int r = 0; r < 4; ++r) {                           \
        const int i = i0 + lg * 4 + r;                                          \
        const int ja = j0 + li, jb = j0 + 16 + li;                              \
        int da = i - ja; if (da < 0) da = -da;                                  \
        int db = i - jb; if (db < 0) db = -db;                                  \
        const bool oka = (ja <= SEQ - 1) && (da <= half || ja == 0);            \
        const bool okb = (jb <= SEQ - 1) && (db <= half);                       \
        const float p0 = exp2f(fmaf(s0[r], SCL, oka ? 0.f : -1e5f));            \
        const float p1 = exp2f(fmaf(s1[r], SCL, okb ? 0.f : -1e5f));            \
        lr[r] += p0 + p1;                                                       \
        P[PAR][lg * 4 + r][li] = f2bf(p0);                                      \
        P[PAR][lg * 4 + r][16 + li] = f2bf(p1);                                 \
      }                                                                         \
    }                                                                           \
    const bfx8 pa = *(const bfx8*)(&P[PAR][li][lg * 8]);                        \
    ctxa[0] = MFMA16(pa, vf0, ctxa[0]);                                         \
    ctxa[1] = MFMA16(pa, vf1, ctxa[1]);                                         \
    ctxa[2] = MFMA16(pa, vf2, ctxa[2]);                                         \
    ctxa[3] = MFMA16(pa, vf3, ctxa[3]);                                         \
  }

__global__ __launch_bounds__(64) void attn_kernel(
    const u16* __restrict__ q, const u16* __restrict__ k,
    const u16* __restrict__ vt, u16* __restrict__ ctx,
    const int* __restrict__ wsz) {
  const int lane = threadIdx.x;
  const int li = lane & 15, lg = lane >> 4;
  const int bid = blockIdx.x;
  const int wid = (bid & 7) * 512 + (bid >> 3);
  const int qt = wid & 127;
  const int h = (wid >> 7) & 15;
  const int b = wid >> 11;
  const int i0 = qt * 16;
  const int bh = b * HEADS + h;
  const int half = wsz[0] >> 1;
  const float SCL = 0.125f * LOG2E;

  __shared__ alignas(16) u16 P[2][16][40];

  const u16* qb = q + (size_t)bh * SEQ * HDIM;
  const u16* kb = k + (size_t)bh * SEQ * HDIM;
  const u16* vb = vt + (size_t)bh * HDIM * SEQ;

  bfx8 qa[2];
#pragma unroll
  for (int ks = 0; ks < 2; ++ks)
    qa[ks] = *(const bfx8*)(qb + (size_t)(i0 + li) * HDIM + ks * 32 + lg * 8);

  int wlo = i0 - half; if (wlo < 0) wlo = 0; wlo &= ~31;
  int whi = i0 + 15 + half; if (whi > SEQ - 1) whi = SEQ - 1;
  const int nc = ((whi - wlo) >> 5) + 1;

  float lr[4] = {0.f, 0.f, 0.f, 0.f};
  f32x4 ctxa[4];
  const f32x4 zero = {0.f, 0.f, 0.f, 0.f};
#pragma unroll
  for (int dt = 0; dt < 4; ++dt) ctxa[dt] = zero;

  bfx8 kfA[4], kfB[4];
  {
    int ja = wlo + li;      if (ja > SEQ - 1) ja = SEQ - 1;
    int jb = wlo + 16 + li; if (jb > SEQ - 1) jb = SEQ - 1;
    kfA[0] = *(const bfx8*)(kb + (size_t)ja * HDIM + lg * 8);
    kfA[1] = *(const bfx8*)(kb + (size_t)ja * HDIM + 32 + lg * 8);
    kfA[2] = *(const bfx8*)(kb + (size_t)jb * HDIM + lg * 8);
    kfA[3] = *(const bfx8*)(kb + (size_t)jb * HDIM + 32 + lg * 8);
  }

  int c = 0;
  while (true) {
    ATTN_STEP(kfA, kfB, 0); if (++c >= nc) break;
    ATTN_STEP(kfB, kfA, 1); if (++c >= nc) break;
  }

#pragma unroll
  for (int r = 0; r < 4; ++r) {
    lr[r] += __shfl_xor(lr[r], 1);
    lr[r] += __shfl_xor(lr[r], 2);
    lr[r] += __shfl_xor(lr[r], 4);
    lr[r] += __shfl_xor(lr[r], 8);
  }

  if (wlo > 0) {
    const bfx8 k0a = *(const bfx8*)(kb + lg * 8);
    const bfx8 k0b = *(const bfx8*)(kb + 32 + lg * 8);
    float sg = 0.f;
#pragma unroll
    for (int e = 0; e < 8; ++e)
      sg += (float)qa[0][e] * (float)k0a[e] + (float)qa[1][e] * (float)k0b[e];
    sg += __shfl_xor(sg, 16);
    sg += __shfl_xor(sg, 32);
    const float pg = exp2f(sg * SCL);
    float v0[4];
#pragma unroll
    for (int dt = 0; dt < 4; ++dt) v0[dt] = bf2f(vb[(size_t)(dt * 16 + li) * SEQ]);
#pragma unroll
    for (int r = 0; r < 4; ++r) {
      const float pq = __shfl(pg, lg * 4 + r);
      lr[r] += pq;
#pragma unroll
      for (int dt = 0; dt < 4; ++dt) ctxa[dt][r] += pq * v0[dt];
    }
  }

#pragma unroll
  for (int r = 0; r < 4; ++r) {
    const float inv = 1.0f / lr[r];
    const int i = i0 + lg * 4 + r;
    const size_t base = ((size_t)b * SEQ + i) * HIDDEN + h * HDIM;
#pragma unroll
    for (int dt = 0; dt < 4; ++dt)
      ctx[base + dt * 16 + li] = f2bf(ctxa[dt][r] * inv);
  }
}

extern "C" void kernel_launch(void* const* d_in, const int* in_sizes, int n_in,
                              void* d_out, int out_size, void* d_ws, size_t ws_size,
                              hipStream_t stream) {
  const float* hs = (const float*)d_in[0];
  const float* Wq = (const float*)d_in[1];
  const float* bq = (const float*)d_in[2];
  const float* Wk = (const float*)d_in[3];
  const float* bk = (const float*)d_in[4];
  const float* Wv = (const float*)d_in[5];
  const float* bv = (const float*)d_in[6];
  const float* Wo = (const float*)d_in[7];
  const float* bo = (const float*)d_in[8];
  const int* wsz  = (const int*)d_in[9];
  float* out = (float*)d_out;

  const int BS = in_sizes[0] / HIDDEN;  // B*S = 4096
  (void)ws_size; (void)n_in; (void)out_size;

  u16* ws    = (u16*)d_ws;
  u16* hsb   = ws;
  u16* wqkvt = hsb + (size_t)BS * HIDDEN;
  u16* wot   = wqkvt + (size_t)3 * HIDDEN * HIDDEN;
  u16* qb    = wot + (size_t)HIDDEN * HIDDEN;
  u16* kb    = qb + (size_t)BS * HIDDEN;
  u16* vtb   = kb + (size_t)BS * HIDDEN;
  u16* ctxb  = hsb;

  cast_bf16_kernel<<<dim3(1024), dim3(256), 0, stream>>>(hs, hsb, BS * HIDDEN / 4);
  transpose_cast4_kernel<<<dim3(16, 16, 4), dim3(256), 0, stream>>>(Wq, Wk, Wv, Wo, wqkvt);

  hipFuncSetAttribute((const void*)gemm_qkv_256_kernel,
                      hipFuncAttributeMaxDynamicSharedMemorySize, 131072);
  gemm_qkv_256_kernel<<<dim3(192), dim3(512), 131072, stream>>>(
      hsb, wqkvt, bq, bk, bv, qb, kb, vtb);

  attn_kernel<<<dim3(4096), dim3(64), 0, stream>>>(qb, kb, vtb, ctxb, wsz);

  gemm_out_kernel<<<dim3(HIDDEN / 128, BS / 128), dim3(256), 0, stream>>>(ctxb, wot, bo, out);
}